// Round 1
// baseline (3065.815 us; speedup 1.0000x reference)
//
#include <hip/hip_runtime.h>
#include <math.h>

#define B_   16
#define C_   512
#define N_   1681
#define CK_  256
#define EPSV 1e-5f
#define SCALE 0.0625f   // Ck^-0.5 = 1/16

#define TM 64
#define TN 64
#define TK 16

// ---------------------------------------------------------------------------
// Kernel 1: Q[b,k,n] = sum_c Wq[k,c]*x[b,c,n] + bq[k]   (and same for K)
// Stored k-major: [B, Ck, N] so the sim GEMM reads both operands along n.
// z = 2*b + which (0=Q, 1=K)
// ---------------------------------------------------------------------------
__global__ __launch_bounds__(256)
void proj_kernel(const float* __restrict__ x,
                 const float* __restrict__ Wq, const float* __restrict__ bq,
                 const float* __restrict__ Wk, const float* __restrict__ bk,
                 float* __restrict__ Q, float* __restrict__ K)
{
    __shared__ __align__(16) float As[TK][TM];  // [c][k-row]
    __shared__ __align__(16) float Bs[TK][TN];  // [c][n]
    const int t  = threadIdx.x;
    const int tx = t & 15, ty = t >> 4;
    const int n0 = blockIdx.x * TN;
    const int m0 = blockIdx.y * TM;
    const int b     = blockIdx.z >> 1;
    const int which = blockIdx.z & 1;
    const float* W    = which ? Wk : Wq;
    const float* bias = which ? bk : bq;
    float*       O    = which ? K  : Q;
    const float* xb = x + (size_t)b * C_ * N_;

    float acc[4][4] = {};
    for (int c0 = 0; c0 < C_; c0 += TK) {
        #pragma unroll
        for (int i = 0; i < 4; ++i) {          // A: 64(k) x 16(c), e = mi*16+kk
            int e = t * 4 + i;
            int kk = e & 15, mi = e >> 4;
            As[kk][mi] = W[(size_t)(m0 + mi) * C_ + c0 + kk];
        }
        #pragma unroll
        for (int i = 0; i < 4; ++i) {          // B: 16(c) x 64(n), e = kk*64+nj
            int e = t * 4 + i;
            int nj = e & 63, kk = e >> 6;
            int n = n0 + nj;
            Bs[kk][nj] = (n < N_) ? xb[(size_t)(c0 + kk) * N_ + n] : 0.0f;
        }
        __syncthreads();
        #pragma unroll
        for (int kk = 0; kk < TK; ++kk) {
            float4 a  = *(const float4*)&As[kk][ty * 4];
            float4 bv = *(const float4*)&Bs[kk][tx * 4];
            float av[4] = {a.x, a.y, a.z, a.w};
            float bb[4] = {bv.x, bv.y, bv.z, bv.w};
            #pragma unroll
            for (int i = 0; i < 4; ++i)
                #pragma unroll
                for (int j = 0; j < 4; ++j)
                    acc[i][j] += av[i] * bb[j];
        }
        __syncthreads();
    }
    #pragma unroll
    for (int i = 0; i < 4; ++i) {
        int mk = m0 + ty * 4 + i;
        float bsv = bias[mk];
        #pragma unroll
        for (int j = 0; j < 4; ++j) {
            int n = n0 + tx * 4 + j;
            if (n < N_)
                O[(size_t)b * CK_ * N_ + (size_t)mk * N_ + n] = acc[i][j] + bsv;
        }
    }
}

// ---------------------------------------------------------------------------
// Kernel 2: S[lb,n,m] = SCALE * sum_k Q[b,k,n]*K[b,k,m]
// ---------------------------------------------------------------------------
__global__ __launch_bounds__(256)
void sim_kernel(const float* __restrict__ Q, const float* __restrict__ K,
                float* __restrict__ S, int b0)
{
    __shared__ __align__(16) float As[TK][TM];  // [k][n]
    __shared__ __align__(16) float Bs[TK][TN];  // [k][m]
    const int t  = threadIdx.x;
    const int tx = t & 15, ty = t >> 4;
    const int mc0 = blockIdx.x * TN;
    const int n0  = blockIdx.y * TM;
    const int lb  = blockIdx.z;
    const int b   = b0 + lb;
    const float* Qb = Q + (size_t)b * CK_ * N_;
    const float* Kb = K + (size_t)b * CK_ * N_;
    float* Sl = S + (size_t)lb * N_ * N_;

    float acc[4][4] = {};
    for (int k0 = 0; k0 < CK_; k0 += TK) {
        #pragma unroll
        for (int i = 0; i < 4; ++i) {
            int e = t * 4 + i;
            int nj = e & 63, kk = e >> 6;
            int n = n0 + nj;
            As[kk][nj] = (n < N_) ? Qb[(size_t)(k0 + kk) * N_ + n] : 0.0f;
        }
        #pragma unroll
        for (int i = 0; i < 4; ++i) {
            int e = t * 4 + i;
            int mj = e & 63, kk = e >> 6;
            int m = mc0 + mj;
            Bs[kk][mj] = (m < N_) ? Kb[(size_t)(k0 + kk) * N_ + m] : 0.0f;
        }
        __syncthreads();
        #pragma unroll
        for (int kk = 0; kk < TK; ++kk) {
            float4 a  = *(const float4*)&As[kk][ty * 4];
            float4 bv = *(const float4*)&Bs[kk][tx * 4];
            float av[4] = {a.x, a.y, a.z, a.w};
            float bb[4] = {bv.x, bv.y, bv.z, bv.w};
            #pragma unroll
            for (int i = 0; i < 4; ++i)
                #pragma unroll
                for (int j = 0; j < 4; ++j)
                    acc[i][j] += av[i] * bb[j];
        }
        __syncthreads();
    }
    #pragma unroll
    for (int i = 0; i < 4; ++i) {
        int n = n0 + ty * 4 + i;
        if (n < N_) {
            #pragma unroll
            for (int j = 0; j < 4; ++j) {
                int m = mc0 + tx * 4 + j;
                if (m < N_) Sl[(size_t)n * N_ + m] = acc[i][j] * SCALE;
            }
        }
    }
}

// ---------------------------------------------------------------------------
// Kernel 3: per-row masked normalize, in place on S.
// sim = S*fg; min over m; x1 = (sim-min)*fg; S <- x1/(sum(x1)+eps)
// ---------------------------------------------------------------------------
__global__ __launch_bounds__(256)
void norm_kernel(const float* __restrict__ fg, float* __restrict__ S, int b0)
{
    __shared__ float ssim[N_];
    __shared__ float sfg[N_];
    __shared__ float red[8];
    const int t  = threadIdx.x;
    const int n  = blockIdx.x;
    const int lb = blockIdx.y;
    const int b  = b0 + lb;
    float*       Srow  = S  + (size_t)lb * N_ * N_ + (size_t)n * N_;
    const float* fgrow = fg + (size_t)b  * N_ * N_ + (size_t)n * N_;

    float lmin = INFINITY;
    for (int m = t; m < N_; m += 256) {
        float fv = fgrow[m];
        float sv = Srow[m] * fv;
        ssim[m] = sv;
        sfg[m]  = fv;
        lmin = fminf(lmin, sv);
    }
    #pragma unroll
    for (int off = 32; off > 0; off >>= 1)
        lmin = fminf(lmin, __shfl_down(lmin, off, 64));
    const int wid = t >> 6;
    if ((t & 63) == 0) red[wid] = lmin;
    __syncthreads();
    const float minv = fminf(fminf(red[0], red[1]), fminf(red[2], red[3]));

    float lsum = 0.0f;
    for (int m = t; m < N_; m += 256) {
        float x1 = (ssim[m] - minv) * sfg[m];
        ssim[m] = x1;
        lsum += x1;
    }
    #pragma unroll
    for (int off = 32; off > 0; off >>= 1)
        lsum += __shfl_down(lsum, off, 64);
    if ((t & 63) == 0) red[4 + wid] = lsum;
    __syncthreads();
    const float Z   = red[4] + red[5] + red[6] + red[7] + EPSV;
    const float inv = 1.0f / Z;
    for (int m = t; m < N_; m += 256) Srow[m] = ssim[m] * inv;
}

// ---------------------------------------------------------------------------
// Kernel 4: out[b,c,n] = gamma * sum_m (S[n,m]+bg[b,n,m]) * x[b,c,m] + x[b,c,n]
// ---------------------------------------------------------------------------
__global__ __launch_bounds__(256)
void ctx_kernel(const float* __restrict__ S, const float* __restrict__ bg,
                const float* __restrict__ x, const float* __restrict__ gamma,
                float* __restrict__ out, int b0)
{
    __shared__ __align__(16) float As[TK][TM];  // [m][n]
    __shared__ __align__(16) float Bs[TK][TN];  // [m][c]
    const int t  = threadIdx.x;
    const int tx = t & 15, ty = t >> 4;
    const int c0 = blockIdx.x * 64;
    const int n0 = blockIdx.y * 64;
    const int lb = blockIdx.z;
    const int b  = b0 + lb;
    const float* Sl  = S  + (size_t)lb * N_ * N_;
    const float* bgb = bg + (size_t)b  * N_ * N_;
    const float* xb  = x  + (size_t)b  * C_ * N_;
    float*       ob  = out + (size_t)b * C_ * N_;

    float acc[4][4] = {};   // [i:n][j:c]
    for (int m0 = 0; m0 < N_; m0 += TK) {
        #pragma unroll
        for (int i = 0; i < 4; ++i) {          // A: 64(n) x 16(m), e = ni*16+mm
            int e = t * 4 + i;
            int mm = e & 15, ni = e >> 4;
            int n = n0 + ni, m = m0 + mm;
            float v = 0.0f;
            if (n < N_ && m < N_) {
                size_t idx = (size_t)n * N_ + m;
                v = Sl[idx] + bgb[idx];
            }
            As[mm][ni] = v;
        }
        #pragma unroll
        for (int i = 0; i < 4; ++i) {          // B: 64(c) x 16(m), e = cj*16+mm
            int e = t * 4 + i;
            int mm = e & 15, cj = e >> 4;
            int m = m0 + mm;
            Bs[mm][cj] = (m < N_) ? xb[(size_t)(c0 + cj) * N_ + m] : 0.0f;
        }
        __syncthreads();
        #pragma unroll
        for (int mm = 0; mm < TK; ++mm) {
            float4 a  = *(const float4*)&As[mm][tx * 4];  // n-frag on tx (write coalescing)
            float4 bv = *(const float4*)&Bs[mm][ty * 4];  // c-frag on ty
            float av[4] = {a.x, a.y, a.z, a.w};
            float bb[4] = {bv.x, bv.y, bv.z, bv.w};
            #pragma unroll
            for (int i = 0; i < 4; ++i)
                #pragma unroll
                for (int j = 0; j < 4; ++j)
                    acc[i][j] += av[i] * bb[j];
        }
        __syncthreads();
    }
    const float g = gamma[0];
    #pragma unroll
    for (int j = 0; j < 4; ++j) {
        int c = c0 + ty * 4 + j;
        #pragma unroll
        for (int i = 0; i < 4; ++i) {
            int n = n0 + tx * 4 + i;
            if (n < N_) {
                size_t idx = (size_t)c * N_ + n;
                ob[idx] = g * acc[i][j] + xb[idx];
            }
        }
    }
}

// ---------------------------------------------------------------------------
extern "C" void kernel_launch(void* const* d_in, const int* in_sizes, int n_in,
                              void* d_out, int out_size, void* d_ws, size_t ws_size,
                              hipStream_t stream)
{
    const float* x     = (const float*)d_in[0];
    const float* fg    = (const float*)d_in[1];
    const float* bg    = (const float*)d_in[2];
    const float* Wq    = (const float*)d_in[3];
    const float* bq    = (const float*)d_in[4];
    const float* Wk    = (const float*)d_in[5];
    const float* bk    = (const float*)d_in[6];
    const float* gamma = (const float*)d_in[7];
    float* out = (float*)d_out;

    float* Q = (float*)d_ws;
    float* K = Q + (size_t)B_ * CK_ * N_;
    float* S = K + (size_t)B_ * CK_ * N_;

    const size_t qk_bytes  = 2ull * B_ * CK_ * N_ * sizeof(float);
    const size_t per_batch = (size_t)N_ * N_ * sizeof(float);
    int chunk = 1;
    if (ws_size > qk_bytes + per_batch) {
        size_t c = (ws_size - qk_bytes) / per_batch;
        chunk = (int)((c > (size_t)B_) ? B_ : c);
        if (chunk < 1) chunk = 1;
    }

    const int ntiles = (N_ + 63) / 64;  // 27

    proj_kernel<<<dim3(ntiles, CK_ / 64, 2 * B_), dim3(256), 0, stream>>>(
        x, Wq, bq, Wk, bk, Q, K);

    for (int b0 = 0; b0 < B_; b0 += chunk) {
        int bc = B_ - b0 < chunk ? B_ - b0 : chunk;
        sim_kernel<<<dim3(ntiles, ntiles, bc), dim3(256), 0, stream>>>(Q, K, S, b0);
        norm_kernel<<<dim3(N_, bc), dim3(256), 0, stream>>>(fg, S, b0);
        ctx_kernel<<<dim3(C_ / 64, ntiles, bc), dim3(256), 0, stream>>>(
            S, bg, x, gamma, out, b0);
    }
}

// Round 2
// 696.147 us; speedup vs baseline: 4.4040x; 4.4040x over previous
//
#include <hip/hip_runtime.h>
#include <math.h>

#define B_   16
#define C_   512
#define N_   1681
#define Np   1792      // padded N (multiple of 128)
#define CK_  256
#define EPSV 1e-5f
#define SCALE 0.0625f  // Ck^-0.5

typedef __bf16 bf16x8 __attribute__((ext_vector_type(8)));
typedef float  f32x4  __attribute__((ext_vector_type(4)));

// ---------------------------------------------------------------------------
// Stage a 128-row x 64-bf16 (128 B) tile global->LDS via async 16B loads.
// LDS chunk (row, col) holds global chunk (row, col ^ (row&7))  [xor swizzle]
// ---------------------------------------------------------------------------
__device__ __forceinline__
void stage_tile(const char* gbase, int ld_bytes, char* lds, int w, int lane)
{
    #pragma unroll
    for (int i = 0; i < 4; ++i) {
        int chunk = (i * 4 + w) * 64 + lane;       // 0..1023
        int row   = chunk >> 3;                    // 8 chunks (128B) per row
        int col   = chunk & 7;
        int scol  = col ^ (row & 7);
        const char* g = gbase + (size_t)row * ld_bytes + scol * 16;
        char* l = lds + (size_t)(i * 4 + w) * 1024;  // wave-uniform base
        __builtin_amdgcn_global_load_lds(
            (const __attribute__((address_space(1))) void*)g,
            (__attribute__((address_space(3))) void*)l, 16, 0, 0);
    }
}

// ---------------------------------------------------------------------------
// 128x128 tile MFMA core: As/Bs are [128 rows][64 k] bf16, xor-swizzled.
// Wave w (0..3): wr=w>>1 selects A-row half, wc=w&1 selects B-row half.
// ---------------------------------------------------------------------------
__device__ __forceinline__
void mma_tile(const __bf16* As, const __bf16* Bs, f32x4 acc[4][4], int wr, int wc, int lane)
{
    const int l15 = lane & 15, quad = lane >> 4;
    #pragma unroll
    for (int kk = 0; kk < 2; ++kk) {
        bf16x8 af[4], bfr[4];
        #pragma unroll
        for (int i = 0; i < 4; ++i) {
            int row = wr * 64 + i * 16 + l15;
            int c   = (kk * 4 + quad) ^ (row & 7);
            af[i] = *(const bf16x8*)(As + row * 64 + c * 8);
        }
        #pragma unroll
        for (int j = 0; j < 4; ++j) {
            int row = wc * 64 + j * 16 + l15;
            int c   = (kk * 4 + quad) ^ (row & 7);
            bfr[j] = *(const bf16x8*)(Bs + row * 64 + c * 8);
        }
        #pragma unroll
        for (int i = 0; i < 4; ++i)
            #pragma unroll
            for (int j = 0; j < 4; ++j)
                acc[i][j] = __builtin_amdgcn_mfma_f32_16x16x32_bf16(
                    af[i], bfr[j], acc[i][j], 0, 0, 0);
    }
}

// ---------------------------------------------------------------------------
// cvt_w: Wh[512][512] bf16 = [Wq; Wk], b2[512] f32 = [bq; bk]
// ---------------------------------------------------------------------------
__global__ __launch_bounds__(256)
void cvt_w_kernel(const float* __restrict__ Wq, const float* __restrict__ Wk,
                  const float* __restrict__ bq, const float* __restrict__ bk,
                  __bf16* __restrict__ Wh, float* __restrict__ b2)
{
    int idx = blockIdx.x * 1024 + threadIdx.x * 4;
    #pragma unroll
    for (int p = 0; p < 4; ++p) {
        int e = idx + p;
        int row = e >> 9, col = e & 511;
        float v = (row < 256) ? Wq[row * 512 + col] : Wk[(row - 256) * 512 + col];
        Wh[e] = (__bf16)v;
    }
    if (blockIdx.x == 0) {
        int t = threadIdx.x;
        b2[t]       = bq[t];
        b2[256 + t] = bk[t];
    }
}

// ---------------------------------------------------------------------------
// cvt_x: xh[b][c][n<Np] bf16 (zero pad), xt[b][n<Np][c] bf16 (zero pad rows)
// ---------------------------------------------------------------------------
__global__ __launch_bounds__(256)
void cvt_x_kernel(const float* __restrict__ x,
                  __bf16* __restrict__ xh, __bf16* __restrict__ xt)
{
    __shared__ float tile[32][33];
    const int t = threadIdx.x;
    const int n0 = blockIdx.x * 32, c0 = blockIdx.y * 32, b = blockIdx.z;
    const float* xb = x + (size_t)b * C_ * N_;
    #pragma unroll
    for (int p = 0; p < 4; ++p) {
        int lin = p * 256 + t;
        int i = lin >> 5, j = lin & 31;     // i: c-offset, j: n-offset
        int n = n0 + j;
        float v = (n < N_) ? xb[(size_t)(c0 + i) * N_ + n] : 0.0f;
        tile[i][j] = v;
        xh[(size_t)b * C_ * Np + (size_t)(c0 + i) * Np + n] = (__bf16)v;
    }
    __syncthreads();
    #pragma unroll
    for (int p = 0; p < 4; ++p) {
        int lin = p * 256 + t;
        int i = lin >> 5, j = lin & 31;     // i: n-offset, j: c-offset
        xt[(size_t)b * Np * C_ + (size_t)(n0 + i) * C_ + (c0 + j)] = (__bf16)tile[j][i];
    }
}

// ---------------------------------------------------------------------------
// proj: QKt[b][n][k2] = sum_c xt[b][n][c] * Wh[k2][c] + b2[k2]
// grid (14 n-tiles, 4 k2-tiles, B)
// ---------------------------------------------------------------------------
__global__ __launch_bounds__(256)
void proj_kernel(const __bf16* __restrict__ xt, const __bf16* __restrict__ Wh,
                 const float* __restrict__ b2, __bf16* __restrict__ QKt)
{
    __shared__ __bf16 As[128 * 64];
    __shared__ __bf16 Bs[128 * 64];
    const int t = threadIdx.x, w = t >> 6, lane = t & 63;
    const int n0 = blockIdx.x * 128, k20 = blockIdx.y * 128, b = blockIdx.z;
    const char* Abase = (const char*)xt + ((size_t)b * Np + n0) * (C_ * 2);
    const char* Bbase = (const char*)Wh + (size_t)k20 * (C_ * 2);

    f32x4 acc[4][4] = {};
    for (int k0 = 0; k0 < C_; k0 += 64) {
        stage_tile(Abase + k0 * 2, C_ * 2, (char*)As, w, lane);
        stage_tile(Bbase + k0 * 2, C_ * 2, (char*)Bs, w, lane);
        __syncthreads();
        mma_tile(As, Bs, acc, w >> 1, w & 1, lane);
        __syncthreads();
    }
    const int l15 = lane & 15, quad = lane >> 4;
    __bf16* ob = QKt + (size_t)b * Np * 512;
    #pragma unroll
    for (int j = 0; j < 4; ++j) {
        int k2 = k20 + (w & 1) * 64 + j * 16 + l15;
        float bias = b2[k2];
        #pragma unroll
        for (int i = 0; i < 4; ++i)
            #pragma unroll
            for (int r = 0; r < 4; ++r) {
                int n = n0 + (w >> 1) * 64 + i * 16 + quad * 4 + r;
                ob[(size_t)n * 512 + k2] = (__bf16)(acc[i][j][r] + bias);
            }
    }
}

// ---------------------------------------------------------------------------
// sim: S[b][n][m] = SCALE * sum_k Qt[n][k] * Kt[m][k]
// Qt = QKt[:, 0:256], Kt = QKt[:, 256:512].  grid (14 m, 14 n, B)
// ---------------------------------------------------------------------------
__global__ __launch_bounds__(256)
void sim_kernel(const __bf16* __restrict__ QKt, __bf16* __restrict__ S)
{
    __shared__ __bf16 As[128 * 64];
    __shared__ __bf16 Bs[128 * 64];
    const int t = threadIdx.x, w = t >> 6, lane = t & 63;
    const int m0 = blockIdx.x * 128, n0 = blockIdx.y * 128, b = blockIdx.z;
    const char* base = (const char*)QKt + (size_t)b * Np * 1024;
    const char* Abase = base + (size_t)n0 * 1024;          // Qt rows
    const char* Bbase = base + (size_t)m0 * 1024 + 512;    // Kt rows (+256 elems)

    f32x4 acc[4][4] = {};
    for (int k0 = 0; k0 < CK_; k0 += 64) {
        stage_tile(Abase + k0 * 2, 1024, (char*)As, w, lane);
        stage_tile(Bbase + k0 * 2, 1024, (char*)Bs, w, lane);
        __syncthreads();
        mma_tile(As, Bs, acc, w >> 1, w & 1, lane);
        __syncthreads();
    }
    const int l15 = lane & 15, quad = lane >> 4;
    __bf16* Sb = S + (size_t)b * Np * Np;
    #pragma unroll
    for (int i = 0; i < 4; ++i)
        #pragma unroll
        for (int r = 0; r < 4; ++r) {
            int n = n0 + (w >> 1) * 64 + i * 16 + quad * 4 + r;
            #pragma unroll
            for (int j = 0; j < 4; ++j) {
                int m = m0 + (w & 1) * 64 + j * 16 + l15;
                Sb[(size_t)n * Np + m] = (__bf16)(acc[i][j][r] * SCALE);
            }
        }
}

// ---------------------------------------------------------------------------
// norm: per row n: sim=S*fg; min; x1=(sim-min)*fg; w=x1/(sum+eps);
//       A'[n][m] = bf16(w + bg), pad cols zeroed.  In place on S.
// ---------------------------------------------------------------------------
__global__ __launch_bounds__(256)
void norm_kernel(const float* __restrict__ fg, const float* __restrict__ bg,
                 __bf16* __restrict__ S)
{
    __shared__ float sx[N_];
    __shared__ float sf[N_];
    __shared__ float red[8];
    const int t = threadIdx.x, n = blockIdx.x, b = blockIdx.y;
    __bf16* Srow = S + (size_t)b * Np * Np + (size_t)n * Np;
    const float* fgrow = fg + ((size_t)b * N_ + n) * N_;
    const float* bgrow = bg + ((size_t)b * N_ + n) * N_;

    float lmin = INFINITY;
    for (int m = t; m < N_; m += 256) {
        float fv = fgrow[m];
        float sv = (float)Srow[m] * fv;
        sx[m] = sv; sf[m] = fv;
        lmin = fminf(lmin, sv);
    }
    #pragma unroll
    for (int off = 32; off > 0; off >>= 1)
        lmin = fminf(lmin, __shfl_down(lmin, off, 64));
    const int wid = t >> 6;
    if ((t & 63) == 0) red[wid] = lmin;
    __syncthreads();
    const float minv = fminf(fminf(red[0], red[1]), fminf(red[2], red[3]));

    float lsum = 0.0f;
    for (int m = t; m < N_; m += 256) {
        float x1 = (sx[m] - minv) * sf[m];
        sx[m] = x1;
        lsum += x1;
    }
    #pragma unroll
    for (int off = 32; off > 0; off >>= 1)
        lsum += __shfl_down(lsum, off, 64);
    if ((t & 63) == 0) red[4 + wid] = lsum;
    __syncthreads();
    const float inv = 1.0f / (red[4] + red[5] + red[6] + red[7] + EPSV);

    for (int m = t; m < N_; m += 256)
        Srow[m] = (__bf16)(sx[m] * inv + bgrow[m]);
    for (int m = N_ + t; m < Np; m += 256)
        Srow[m] = (__bf16)0.0f;
}

// ---------------------------------------------------------------------------
// ctx: out[b][c][n] = gamma * sum_m xh[c][m] * A'[n][m] + x[b][c][n]
// grid (4 c-tiles, 14 n-tiles, B)
// ---------------------------------------------------------------------------
__global__ __launch_bounds__(256)
void ctx_kernel(const __bf16* __restrict__ xh, const __bf16* __restrict__ Ap,
                const float* __restrict__ x, const float* __restrict__ gamma,
                float* __restrict__ out)
{
    __shared__ __bf16 As[128 * 64];
    __shared__ __bf16 Bs[128 * 64];
    const int t = threadIdx.x, w = t >> 6, lane = t & 63;
    const int c0 = blockIdx.x * 128, n0 = blockIdx.y * 128, b = blockIdx.z;
    const char* Abase = (const char*)xh + ((size_t)b * C_ + c0) * (Np * 2);
    const char* Bbase = (const char*)Ap + ((size_t)b * Np + n0) * (Np * 2);

    f32x4 acc[4][4] = {};
    for (int k0 = 0; k0 < Np; k0 += 64) {
        stage_tile(Abase + k0 * 2, Np * 2, (char*)As, w, lane);
        stage_tile(Bbase + k0 * 2, Np * 2, (char*)Bs, w, lane);
        __syncthreads();
        mma_tile(As, Bs, acc, w >> 1, w & 1, lane);
        __syncthreads();
    }
    const int l15 = lane & 15, quad = lane >> 4;
    const float g = gamma[0];
    const float* xb = x + (size_t)b * C_ * N_;
    float* ob = out + (size_t)b * C_ * N_;
    #pragma unroll
    for (int i = 0; i < 4; ++i)
        #pragma unroll
        for (int r = 0; r < 4; ++r) {
            int c = c0 + (w >> 1) * 64 + i * 16 + quad * 4 + r;
            #pragma unroll
            for (int j = 0; j < 4; ++j) {
                int n = n0 + (w & 1) * 64 + j * 16 + l15;
                if (n < N_) {
                    size_t idx = (size_t)c * N_ + n;
                    ob[idx] = g * acc[i][j][r] + xb[idx];
                }
            }
        }
}

// ---------------------------------------------------------------------------
extern "C" void kernel_launch(void* const* d_in, const int* in_sizes, int n_in,
                              void* d_out, int out_size, void* d_ws, size_t ws_size,
                              hipStream_t stream)
{
    const float* x     = (const float*)d_in[0];
    const float* fg    = (const float*)d_in[1];
    const float* bg    = (const float*)d_in[2];
    const float* Wq    = (const float*)d_in[3];
    const float* bq    = (const float*)d_in[4];
    const float* Wk    = (const float*)d_in[5];
    const float* bk    = (const float*)d_in[6];
    const float* gamma = (const float*)d_in[7];
    float* out = (float*)d_out;

    char* p = (char*)d_ws;
    __bf16* xh  = (__bf16*)p; p += (size_t)B_ * C_ * Np * 2;   // 29.4 MB
    __bf16* xt  = (__bf16*)p; p += (size_t)B_ * Np * C_ * 2;   // 29.4 MB
    __bf16* QKt = (__bf16*)p; p += (size_t)B_ * Np * 512 * 2;  // 29.4 MB
    __bf16* S   = (__bf16*)p; p += (size_t)B_ * Np * Np * 2;   // 102.8 MB
    __bf16* Wh  = (__bf16*)p; p += (size_t)512 * 512 * 2;      // 0.5 MB
    float*  b2  = (float*)p;                                   // 2 KB

    cvt_w_kernel<<<dim3(256), dim3(256), 0, stream>>>(Wq, Wk, bq, bk, Wh, b2);
    cvt_x_kernel<<<dim3(Np / 32, C_ / 32, B_), dim3(256), 0, stream>>>(x, xh, xt);
    proj_kernel<<<dim3(Np / 128, 4, B_), dim3(256), 0, stream>>>(xt, Wh, b2, QKt);
    sim_kernel<<<dim3(Np / 128, Np / 128, B_), dim3(256), 0, stream>>>(QKt, S);
    norm_kernel<<<dim3(N_, B_), dim3(256), 0, stream>>>(fg, bg, S);
    ctx_kernel<<<dim3(C_ / 128, Np / 128, B_), dim3(256), 0, stream>>>(xh, S, x, gamma, out);
}